// Round 11
// baseline (116.527 us; speedup 1.0000x reference)
//
#include <hip/hip_runtime.h>

#define B_ 2
#define Q_ 2048
#define K_ 2048
#define H_ 16
#define D_ 64
#define HD_ (H_ * D_)
#define BQH (B_ * Q_ * H_)

// Q pre-scale: (1/sqrt(64)) * log2(e)  -> scores in log2 units; softmax uses
// raw v_exp_f32 (2^x) with no per-element multiply.
#define QSCALE 0.18033688011112042f
#define DEFER_THR 10.0f   // log2-units; P bounded by 2^10, fine in bf16/f32

typedef __bf16 bf16_t;
typedef __attribute__((ext_vector_type(8))) __bf16 bf16x8;
typedef __attribute__((ext_vector_type(4))) __bf16 bf16x4;
typedef __attribute__((ext_vector_type(4))) float f32x4;
typedef __attribute__((ext_vector_type(4))) unsigned int u32x4;

// Raw barrier: drains LDS ops only; global register-prefetch stays in flight.
#define SBAR() do {                                         \
    __builtin_amdgcn_sched_barrier(0);                      \
    asm volatile("s_waitcnt lgkmcnt(0)" ::: "memory");      \
    __builtin_amdgcn_s_barrier();                           \
    __builtin_amdgcn_sched_barrier(0);                      \
} while (0)

// Swizzled byte offset for a [N][64] bf16 tile (row stride 128 B).
// XOR bits 4-6 with row&7: bijective, keeps 16B granules, kills bank conflicts.
__device__ __forceinline__ int swz(int row, int colByte) {
    return (row * 128 + colByte) ^ ((row & 7) << 4);
}

// F=2 kernel: 256 threads = 4 waves, each wave owns 32 q rows (two 16-row
// fragments) so every K/V ds_read_b128 feeds TWO MFMAs. P never touches LDS:
// cvt_pk + permlane{32,16}_swap redistribute C-layout P into B-fragment
// layout in registers (pure VALU — off the saturated LDS pipe).
// NOTE: min-waves 4 -> VGPR cap 128 (r9 lesson: higher min-waves spills).
template<bool SPLITK>
__global__ __launch_bounds__(256, 4) void attn_fwd_kernel(
    const float* __restrict__ qs, const float* __restrict__ ks,
    const float* __restrict__ vs, const int* __restrict__ valid_lens,
    float* __restrict__ out, bf16_t* __restrict__ po, float* __restrict__ ml)
{
    int qt, split;
    if constexpr (SPLITK) { qt = blockIdx.x >> 1; split = blockIdx.x & 1; }
    else                  { qt = blockIdx.x;      split = 0; }
    const int h    = blockIdx.y;
    const int b    = blockIdx.z;
    const int tid  = threadIdx.x;
    const int wave = tid >> 6;     // 0..3
    const int lane = tid & 63;
    const int l16  = lane & 15;
    const int lhi  = lane >> 4;    // 0..3

    const int valid  = valid_lens[b];
    const int ntiles = (valid + 63) >> 6;
    int tbeg = 0, tend = ntiles;
    if constexpr (SPLITK) {
        const int half = (ntiles + 1) >> 1;
        tbeg = split ? half : 0;
        tend = split ? ntiles : half;
    }

    const int qrow0 = qt * 128 + wave * 32 + l16;   // frag f adds +16

    if constexpr (SPLITK) {
        if (tbeg >= tend) {    // empty split: weight-0 sentinel
            if (lhi == 0) {
                #pragma unroll
                for (int f = 0; f < 2; ++f) {
                    const size_t slot = ((((size_t)split * B_ + b) * Q_ + qrow0 + f * 16) * H_ + h) * 2;
                    ml[slot] = -1e30f; ml[slot + 1] = 0.f;
                }
            }
            return;
        }
    }

    __shared__ bf16_t k_lds[2][64 * 64];    // [buf][key][d], swizzled
    __shared__ bf16_t v_lds[2][64 * 64];    // [buf][d][key] transposed, swizzled

    // ---- Q fragments (lane = row l16, k-dim d = dh*32+lhi*8+j), scale folded.
    bf16x8 a_q[2][2];
    #pragma unroll
    for (int f = 0; f < 2; ++f) {
        const float* qp = qs + (((size_t)b * Q_ + qrow0 + f * 16) * H_ + h) * D_;
        #pragma unroll
        for (int dh = 0; dh < 2; ++dh) {
            const f32x4* q4 = (const f32x4*)(qp + dh * 32 + lhi * 8);
            f32x4 lo = q4[0], hi = q4[1];
            #pragma unroll
            for (int j = 0; j < 4; ++j) {
                a_q[f][dh][j]     = (bf16_t)(lo[j] * QSCALE);
                a_q[f][dh][4 + j] = (bf16_t)(hi[j] * QSCALE);
            }
        }
    }

    // O accumulator (swapped PV C-layout): lane = q-col l16, d = t*16+lhi*4+r.
    f32x4 o_acc[2][4];
    #pragma unroll
    for (int f = 0; f < 2; ++f)
        #pragma unroll
        for (int t = 0; t < 4; ++t) o_acc[f][t] = (f32x4){0.f, 0.f, 0.f, 0.f};
    float m_r[2] = {-1e30f, -1e30f}, l_part[2] = {0.f, 0.f};

    const float* kb = ks + ((size_t)b * K_ * H_ + h) * D_;
    const float* vg = vs + ((size_t)b * K_ * H_ + h) * D_;

    // staging role split (wave-uniform): waves 0-1 stage K, waves 2-3 stage V
    const bool kRole = (tid < 128);
    const int  st    = kRole ? tid : (tid - 128);   // 0..127
    const int  krow  = st >> 1;                     // 0..63 (key)
    const int  kcolf = (st & 1) * 32;               // float col base (32/thread)
    const int  vr    = (st & 15) * 4;               // key base (4 rows)
    const int  vc    = (st >> 4) * 8;               // d base (8 cols)

    f32x4 reg[8];   // in-flight next tile (lives across the barrier)

    auto issue_loads = [&](int kt) {
        if (kRole) {
            const float* ksrc = kb + (size_t)(kt * 64 + krow) * HD_ + kcolf;
            #pragma unroll
            for (int i = 0; i < 8; ++i) reg[i] = ((const f32x4*)ksrc)[i];
        } else {
            #pragma unroll
            for (int i = 0; i < 4; ++i) {
                const float* vsrc = vg + (size_t)(kt * 64 + vr + i) * HD_ + vc;
                reg[2 * i]     = ((const f32x4*)vsrc)[0];
                reg[2 * i + 1] = ((const f32x4*)vsrc)[1];
            }
        }
    };

    auto write_tile = [&](int bi) {
        if (kRole) {
            char* kdst = (char*)&k_lds[bi][0];
            #pragma unroll
            for (int p = 0; p < 4; ++p) {
                bf16x8 w;
                #pragma unroll
                for (int j = 0; j < 4; ++j) {
                    w[j]     = (bf16_t)reg[2 * p][j];
                    w[4 + j] = (bf16_t)reg[2 * p + 1][j];
                }
                *(bf16x8*)(kdst + swz(krow, kcolf * 2 + p * 16)) = w;
            }
        } else {
            char* vdst = (char*)&v_lds[bi][0];
            #pragma unroll
            for (int j = 0; j < 4; ++j) {
                bf16x4 w;
                #pragma unroll
                for (int r = 0; r < 4; ++r) w[r] = (bf16_t)reg[2 * r][j];
                *(bf16x4*)(vdst + swz(vc + j, vr * 2)) = w;
            }
            #pragma unroll
            for (int j = 0; j < 4; ++j) {
                bf16x4 w;
                #pragma unroll
                for (int r = 0; r < 4; ++r) w[r] = (bf16_t)reg[2 * r + 1][j];
                *(bf16x4*)(vdst + swz(vc + 4 + j, vr * 2)) = w;
            }
        }
    };

    // prologue: first tile straight to LDS
    issue_loads(tbeg);
    write_tile(0);
    int cur = 0;

    for (int kt = tbeg; kt < tend; ++kt) {
        const bool more = (kt + 1 < tend);
        if (more) issue_loads(kt + 1);   // in flight across SBAR (no vmcnt drain)
        SBAR();

        char* const kbase = (char*)&k_lds[cur][0];
        char* const vbase = (char*)&v_lds[cur][0];

        // ---- S^T = K Q^T: lane = q-row l16, keys n*16+lhi*4+r. Each K-frag
        // read feeds both q-fragments.
        f32x4 s[2][4];
        #pragma unroll
        for (int f = 0; f < 2; ++f)
            #pragma unroll
            for (int n = 0; n < 4; ++n) s[f][n] = (f32x4){0.f, 0.f, 0.f, 0.f};
        __builtin_amdgcn_s_setprio(1);
        #pragma unroll
        for (int n = 0; n < 4; ++n) {
            #pragma unroll
            for (int dh = 0; dh < 2; ++dh) {
                bf16x8 ak = *(const bf16x8*)(kbase + swz(n * 16 + l16, dh * 64 + lhi * 16));
                s[0][n] = __builtin_amdgcn_mfma_f32_16x16x32_bf16(ak, a_q[0][dh], s[0][n], 0, 0, 0);
                s[1][n] = __builtin_amdgcn_mfma_f32_16x16x32_bf16(ak, a_q[1][dh], s[1][n], 0, 0, 0);
            }
        }
        __builtin_amdgcn_s_setprio(0);

        // ---- mask only on the boundary tile (uniform branch) ----
        if (kt * 64 + 64 > valid) {
            #pragma unroll
            for (int n = 0; n < 4; ++n) {
                const int kbase_i = kt * 64 + n * 16 + lhi * 4;
                #pragma unroll
                for (int r = 0; r < 4; ++r)
                    if (kbase_i + r >= valid) { s[0][n][r] = -1e30f; s[1][n][r] = -1e30f; }
            }
        }

        // ---- deferred-max online softmax, per-fragment lane-local state ----
        float lm[2];
        #pragma unroll
        for (int f = 0; f < 2; ++f) {
            lm[f] = s[f][0][0];
            #pragma unroll
            for (int n = 0; n < 4; ++n)
                #pragma unroll
                for (int r = 0; r < 4; ++r) lm[f] = fmaxf(lm[f], s[f][n][r]);
        }
        if (__any((lm[0] > m_r[0] + DEFER_THR) || (lm[1] > m_r[1] + DEFER_THR))) {
            #pragma unroll
            for (int f = 0; f < 2; ++f) {
                float rm = fmaxf(lm[f], __shfl_xor(lm[f], 16, 64));
                rm = fmaxf(rm, __shfl_xor(rm, 32, 64));
                const float mnew  = fmaxf(m_r[f], rm);
                const float alpha = __builtin_amdgcn_exp2f(m_r[f] - mnew);
                m_r[f] = mnew;
                l_part[f] *= alpha;
                #pragma unroll
                for (int t = 0; t < 4; ++t) o_acc[f][t] *= alpha;
            }
        }

        // ---- P = 2^(s-m) -> bf16 B-fragments IN REGISTERS via cvt_pk +
        // permlane swaps (no LDS). pk[n][i] = keys n*16+lhi*4+{2i,2i+1}.
        // swap32(a,b); swap16(a,b): a -> keys g*8+{0..3} slice, b -> g*8+{4..7}.
        bf16x8 pb[2][2];
        #pragma unroll
        for (int f = 0; f < 2; ++f) {
            float psum = 0.f;
            unsigned pk[4][2];
            #pragma unroll
            for (int n = 0; n < 4; ++n) {
                float e0 = __builtin_amdgcn_exp2f(s[f][n][0] - m_r[f]);
                float e1 = __builtin_amdgcn_exp2f(s[f][n][1] - m_r[f]);
                float e2 = __builtin_amdgcn_exp2f(s[f][n][2] - m_r[f]);
                float e3 = __builtin_amdgcn_exp2f(s[f][n][3] - m_r[f]);
                psum += (e0 + e1) + (e2 + e3);
                asm("v_cvt_pk_bf16_f32 %0, %1, %2" : "=v"(pk[n][0]) : "v"(e0), "v"(e1));
                asm("v_cvt_pk_bf16_f32 %0, %1, %2" : "=v"(pk[n][1]) : "v"(e2), "v"(e3));
            }
            l_part[f] += psum;
            #pragma unroll
            for (int kk = 0; kk < 2; ++kk) {
                unsigned a0 = pk[2 * kk][0],     a1 = pk[2 * kk][1];
                unsigned b0 = pk[2 * kk + 1][0], b1 = pk[2 * kk + 1][1];
                asm("v_permlane32_swap_b32 %0, %1" : "+v"(a0), "+v"(b0));
                asm("v_permlane16_swap_b32 %0, %1" : "+v"(a0), "+v"(b0));
                asm("v_permlane32_swap_b32 %0, %1" : "+v"(a1), "+v"(b1));
                asm("v_permlane16_swap_b32 %0, %1" : "+v"(a1), "+v"(b1));
                u32x4 words = {a0, a1, b0, b1};   // j01, j23, j45, j67
                pb[f][kk] = __builtin_bit_cast(bf16x8, words);
            }
        }

        // ---- PV swapped: O^T += V^T P^T. Each V-frag read feeds both frags.
        __builtin_amdgcn_s_setprio(1);
        #pragma unroll
        for (int t = 0; t < 4; ++t) {
            #pragma unroll
            for (int kk = 0; kk < 2; ++kk) {
                bf16x8 vb = *(const bf16x8*)(vbase + swz(t * 16 + l16, kk * 64 + lhi * 16));
                o_acc[0][t] = __builtin_amdgcn_mfma_f32_16x16x32_bf16(vb, pb[0][kk], o_acc[0][t], 0, 0, 0);
                o_acc[1][t] = __builtin_amdgcn_mfma_f32_16x16x32_bf16(vb, pb[1][kk], o_acc[1][t], 0, 0, 0);
            }
        }
        __builtin_amdgcn_s_setprio(0);

        // regs -> LDS for next tile; vmcnt paid HERE (after full compute phase)
        if (more) write_tile(cur ^ 1);
        cur ^= 1;
    }

    // ---- epilogue: finish l across lhi groups, store per fragment ----
    #pragma unroll
    for (int f = 0; f < 2; ++f) {
        float l = l_part[f];
        l += __shfl_xor(l, 16, 64);
        l += __shfl_xor(l, 32, 64);
        const int qrow = qrow0 + f * 16;
        if constexpr (SPLITK) {
            if (lhi == 0) {
                const size_t slot = ((((size_t)split * B_ + b) * Q_ + qrow) * H_ + h) * 2;
                ml[slot] = m_r[f]; ml[slot + 1] = l;
            }
            bf16_t* pop = po + ((((size_t)split * B_ + b) * Q_ + qrow) * H_ + h) * D_;
            #pragma unroll
            for (int t = 0; t < 4; ++t) {
                bf16x4 w;
                #pragma unroll
                for (int r = 0; r < 4; ++r) w[r] = (bf16_t)o_acc[f][t][r];
                *(bf16x4*)(pop + t * 16 + lhi * 4) = w;
            }
        } else {
            const float inv = 1.f / l;
            float* op = out + (((size_t)b * Q_ + qrow) * H_ + h) * D_;
            #pragma unroll
            for (int t = 0; t < 4; ++t) {
                f32x4 res = o_acc[f][t];
                #pragma unroll
                for (int r = 0; r < 4; ++r) res[r] *= inv;
                *(f32x4*)(op + t * 16 + lhi * 4) = res;
            }
        }
    }
}

// Merge the two splits: out = (2^(m0-M) O0 + 2^(m1-M) O1) / (2^(m0-M) l0 + 2^(m1-M) l1).
__global__ __launch_bounds__(256) void attn_combine(
    const bf16_t* __restrict__ po, const float* __restrict__ ml,
    float* __restrict__ out)
{
    const int idx  = blockIdx.x * 256 + threadIdx.x;   // < BQH*16
    const int dv   = idx & 15;                         // which f32x4 within D
    const int slot = idx >> 4;                         // (b*Q+q)*H+h
    const float2 ml0 = ((const float2*)ml)[slot];
    const float2 ml1 = ((const float2*)ml)[BQH + slot];
    const float M   = fmaxf(ml0.x, ml1.x);
    const float c0  = exp2f(ml0.x - M);
    const float c1  = exp2f(ml1.x - M);   // 0 exactly when split empty (m=-1e30)
    const float inv = 1.f / (c0 * ml0.y + c1 * ml1.y);
    bf16x4 p0 = *(const bf16x4*)(po + (size_t)slot * D_ + dv * 4);
    bf16x4 p1 = *(const bf16x4*)(po + (size_t)BQH * D_ + (size_t)slot * D_ + dv * 4);
    f32x4 o;
    #pragma unroll
    for (int r = 0; r < 4; ++r)
        o[r] = (c0 * (float)p0[r] + c1 * (float)p1[r]) * inv;
    *(f32x4*)(out + (size_t)slot * D_ + dv * 4) = o;
}

extern "C" void kernel_launch(void* const* d_in, const int* in_sizes, int n_in,
                              void* d_out, int out_size, void* d_ws, size_t ws_size,
                              hipStream_t stream) {
    const float* qs = (const float*)d_in[0];
    const float* ks = (const float*)d_in[1];
    const float* vs = (const float*)d_in[2];
    const int*   vl = (const int*)d_in[3];
    float*       out = (float*)d_out;

    const size_t po_bytes = (size_t)2 * BQH * D_ * sizeof(bf16_t);   // 16.78 MB
    const size_t ml_bytes = (size_t)2 * BQH * 2 * sizeof(float);     //  2.10 MB
    if (ws_size >= po_bytes + ml_bytes) {
        bf16_t* po = (bf16_t*)d_ws;
        float*  ml = (float*)((char*)d_ws + po_bytes);
        attn_fwd_kernel<true><<<dim3(32, 16, 2), 256, 0, stream>>>(qs, ks, vs, vl, nullptr, po, ml);
        attn_combine<<<dim3((BQH * 16) / 256), 256, 0, stream>>>(po, ml, out);
    } else {
        attn_fwd_kernel<false><<<dim3(16, 16, 2), 256, 0, stream>>>(qs, ks, vs, vl, out, nullptr, nullptr);
    }
}

// Round 12
// 73.473 us; speedup vs baseline: 1.5860x; 1.5860x over previous
//
#include <hip/hip_runtime.h>

#define B_ 2
#define Q_ 2048
#define K_ 2048
#define H_ 16
#define D_ 64
#define HD_ (H_ * D_)
#define BQH (B_ * Q_ * H_)

// Q pre-scale: (1/sqrt(64)) * log2(e)  -> scores in log2 units; softmax uses
// raw v_exp_f32 (2^x) with no per-element multiply.
#define QSCALE 0.18033688011112042f
#define DEFER_THR 10.0f   // log2-units; P bounded by 2^10, fine in bf16/f32

typedef __bf16 bf16_t;
typedef __attribute__((ext_vector_type(8))) __bf16 bf16x8;
typedef __attribute__((ext_vector_type(4))) __bf16 bf16x4;
typedef __attribute__((ext_vector_type(4))) float f32x4;
typedef __attribute__((ext_vector_type(4))) unsigned int u32x4;

// Raw barrier: drains LDS ops only; global register-prefetch stays in flight.
#define SBAR() do {                                         \
    __builtin_amdgcn_sched_barrier(0);                      \
    asm volatile("s_waitcnt lgkmcnt(0)" ::: "memory");      \
    __builtin_amdgcn_s_barrier();                           \
    __builtin_amdgcn_sched_barrier(0);                      \
} while (0)

// Swizzled byte offset for a [N][64] bf16 tile (row stride 128 B).
// XOR bits 4-6 with row&7: bijective, keeps 16B granules, kills bank conflicts.
__device__ __forceinline__ int swz(int row, int colByte) {
    return (row * 128 + colByte) ^ ((row & 7) << 4);
}

// 512 threads = 8 waves, each wave owns 32 q rows (two 16-row fragments):
// every K/V ds_read_b128 feeds TWO MFMAs, staging amortized over 256 q rows.
// P never touches LDS (cvt_pk + permlane swaps, pure VALU).
// reg[4] prefetch (not reg[8]) keeps peak VGPR < 128 — r11 spilled at 145+.
template<bool SPLITK>
__global__ __launch_bounds__(512, 4) void attn_fwd_kernel(
    const float* __restrict__ qs, const float* __restrict__ ks,
    const float* __restrict__ vs, const int* __restrict__ valid_lens,
    float* __restrict__ out, bf16_t* __restrict__ po, float* __restrict__ ml)
{
    int qt, split;
    if constexpr (SPLITK) { qt = blockIdx.x >> 1; split = blockIdx.x & 1; }
    else                  { qt = blockIdx.x;      split = 0; }
    const int h    = blockIdx.y;
    const int b    = blockIdx.z;
    const int tid  = threadIdx.x;
    const int wave = tid >> 6;     // 0..7, each owns 32 q rows
    const int lane = tid & 63;
    const int l16  = lane & 15;
    const int lhi  = lane >> 4;    // 0..3

    const int valid  = valid_lens[b];
    const int ntiles = (valid + 63) >> 6;
    int tbeg = 0, tend = ntiles;
    if constexpr (SPLITK) {
        const int half = (ntiles + 1) >> 1;
        tbeg = split ? half : 0;
        tend = split ? ntiles : half;
    }

    const int qrow0 = qt * 256 + wave * 32 + l16;   // frag f adds +16

    if constexpr (SPLITK) {
        if (tbeg >= tend) {    // empty split: weight-0 sentinel
            if (lhi == 0) {
                #pragma unroll
                for (int f = 0; f < 2; ++f) {
                    const size_t slot = ((((size_t)split * B_ + b) * Q_ + qrow0 + f * 16) * H_ + h) * 2;
                    ml[slot] = -1e30f; ml[slot + 1] = 0.f;
                }
            }
            return;
        }
    }

    __shared__ bf16_t k_lds[2][64 * 64];    // [buf][key][d], swizzled
    __shared__ bf16_t v_lds[2][64 * 64];    // [buf][d][key] transposed, swizzled

    // ---- Q fragments (lane = row l16, k-dim d = dh*32+lhi*8+j), scale folded.
    bf16x8 a_q[2][2];
    #pragma unroll
    for (int f = 0; f < 2; ++f) {
        const float* qp = qs + (((size_t)b * Q_ + qrow0 + f * 16) * H_ + h) * D_;
        #pragma unroll
        for (int dh = 0; dh < 2; ++dh) {
            const f32x4* q4 = (const f32x4*)(qp + dh * 32 + lhi * 8);
            f32x4 lo = q4[0], hi = q4[1];
            #pragma unroll
            for (int j = 0; j < 4; ++j) {
                a_q[f][dh][j]     = (bf16_t)(lo[j] * QSCALE);
                a_q[f][dh][4 + j] = (bf16_t)(hi[j] * QSCALE);
            }
        }
    }

    // O accumulator (swapped PV C-layout): lane = q-col l16, d = t*16+lhi*4+r.
    f32x4 o_acc[2][4];
    #pragma unroll
    for (int f = 0; f < 2; ++f)
        #pragma unroll
        for (int t = 0; t < 4; ++t) o_acc[f][t] = (f32x4){0.f, 0.f, 0.f, 0.f};
    float m_r[2] = {-1e30f, -1e30f}, l_part[2] = {0.f, 0.f};

    const float* kb = ks + ((size_t)b * K_ * H_ + h) * D_;
    const float* vg = vs + ((size_t)b * K_ * H_ + h) * D_;

    // staging role split (wave-uniform): waves 0-3 stage K, waves 4-7 stage V
    const bool kRole = (tid < 256);
    const int  st    = kRole ? tid : (tid - 256);   // 0..255
    const int  krow  = st >> 2;                     // 0..63 (key)
    const int  kcolf = (st & 3) * 16;               // float col base
    const int  vr    = (st & 15) * 4;               // key base (4 rows)
    const int  vc    = (st >> 4) * 4;               // d base (4 cols)

    f32x4 reg[4];   // in-flight next tile (lives across the barrier)

    auto issue_loads = [&](int kt) {
        if (kRole) {
            const float* ksrc = kb + (size_t)(kt * 64 + krow) * HD_ + kcolf;
            #pragma unroll
            for (int i = 0; i < 4; ++i) reg[i] = ((const f32x4*)ksrc)[i];
        } else {
            #pragma unroll
            for (int i = 0; i < 4; ++i)
                reg[i] = *(const f32x4*)(vg + (size_t)(kt * 64 + vr + i) * HD_ + vc);
        }
    };

    auto write_tile = [&](int bi) {
        if (kRole) {
            char* kdst = (char*)&k_lds[bi][0];
            bf16x8 lo, hi;
            #pragma unroll
            for (int j = 0; j < 4; ++j) {
                lo[j] = (bf16_t)reg[0][j]; lo[4 + j] = (bf16_t)reg[1][j];
                hi[j] = (bf16_t)reg[2][j]; hi[4 + j] = (bf16_t)reg[3][j];
            }
            *(bf16x8*)(kdst + swz(krow, kcolf * 2))      = lo;
            *(bf16x8*)(kdst + swz(krow, kcolf * 2 + 16)) = hi;
        } else {
            char* vdst = (char*)&v_lds[bi][0];
            #pragma unroll
            for (int j = 0; j < 4; ++j) {
                bf16x4 w;
                w[0] = (bf16_t)reg[0][j]; w[1] = (bf16_t)reg[1][j];
                w[2] = (bf16_t)reg[2][j]; w[3] = (bf16_t)reg[3][j];
                *(bf16x4*)(vdst + swz(vc + j, vr * 2)) = w;
            }
        }
    };

    // prologue: first tile straight to LDS
    issue_loads(tbeg);
    write_tile(0);
    int cur = 0;

    for (int kt = tbeg; kt < tend; ++kt) {
        const bool more = (kt + 1 < tend);
        if (more) issue_loads(kt + 1);   // in flight across SBAR (no vmcnt drain)
        SBAR();

        char* const kbase = (char*)&k_lds[cur][0];
        char* const vbase = (char*)&v_lds[cur][0];

        // ---- S^T = K Q^T: lane = q-row l16, keys n*16+lhi*4+r. Each K-frag
        // read feeds both q-fragments.
        f32x4 s[2][4];
        #pragma unroll
        for (int f = 0; f < 2; ++f)
            #pragma unroll
            for (int n = 0; n < 4; ++n) s[f][n] = (f32x4){0.f, 0.f, 0.f, 0.f};
        __builtin_amdgcn_s_setprio(1);
        #pragma unroll
        for (int n = 0; n < 4; ++n) {
            #pragma unroll
            for (int dh = 0; dh < 2; ++dh) {
                bf16x8 ak = *(const bf16x8*)(kbase + swz(n * 16 + l16, dh * 64 + lhi * 16));
                s[0][n] = __builtin_amdgcn_mfma_f32_16x16x32_bf16(ak, a_q[0][dh], s[0][n], 0, 0, 0);
                s[1][n] = __builtin_amdgcn_mfma_f32_16x16x32_bf16(ak, a_q[1][dh], s[1][n], 0, 0, 0);
            }
        }
        __builtin_amdgcn_s_setprio(0);

        // ---- mask only on the boundary tile (uniform branch) ----
        if (kt * 64 + 64 > valid) {
            #pragma unroll
            for (int n = 0; n < 4; ++n) {
                const int kbase_i = kt * 64 + n * 16 + lhi * 4;
                #pragma unroll
                for (int r = 0; r < 4; ++r)
                    if (kbase_i + r >= valid) { s[0][n][r] = -1e30f; s[1][n][r] = -1e30f; }
            }
        }

        // ---- deferred-max online softmax, per-fragment lane-local state ----
        float lm[2];
        #pragma unroll
        for (int f = 0; f < 2; ++f) {
            lm[f] = s[f][0][0];
            #pragma unroll
            for (int n = 0; n < 4; ++n)
                #pragma unroll
                for (int r = 0; r < 4; ++r) lm[f] = fmaxf(lm[f], s[f][n][r]);
        }
        if (__any((lm[0] > m_r[0] + DEFER_THR) || (lm[1] > m_r[1] + DEFER_THR))) {
            #pragma unroll
            for (int f = 0; f < 2; ++f) {
                float rm = fmaxf(lm[f], __shfl_xor(lm[f], 16, 64));
                rm = fmaxf(rm, __shfl_xor(rm, 32, 64));
                const float mnew  = fmaxf(m_r[f], rm);
                const float alpha = __builtin_amdgcn_exp2f(m_r[f] - mnew);
                m_r[f] = mnew;
                l_part[f] *= alpha;
                #pragma unroll
                for (int t = 0; t < 4; ++t) o_acc[f][t] *= alpha;
            }
        }

        // ---- P = 2^(s-m) -> bf16 B-fragments IN REGISTERS via cvt_pk +
        // permlane swaps (no LDS). Verified correct in r11 (absmax unchanged,
        // bank conflicts -> 0).
        bf16x8 pb[2][2];
        #pragma unroll
        for (int f = 0; f < 2; ++f) {
            float psum = 0.f;
            unsigned pk[4][2];
            #pragma unroll
            for (int n = 0; n < 4; ++n) {
                float e0 = __builtin_amdgcn_exp2f(s[f][n][0] - m_r[f]);
                float e1 = __builtin_amdgcn_exp2f(s[f][n][1] - m_r[f]);
                float e2 = __builtin_amdgcn_exp2f(s[f][n][2] - m_r[f]);
                float e3 = __builtin_amdgcn_exp2f(s[f][n][3] - m_r[f]);
                psum += (e0 + e1) + (e2 + e3);
                asm("v_cvt_pk_bf16_f32 %0, %1, %2" : "=v"(pk[n][0]) : "v"(e0), "v"(e1));
                asm("v_cvt_pk_bf16_f32 %0, %1, %2" : "=v"(pk[n][1]) : "v"(e2), "v"(e3));
            }
            l_part[f] += psum;
            #pragma unroll
            for (int kk = 0; kk < 2; ++kk) {
                unsigned a0 = pk[2 * kk][0],     a1 = pk[2 * kk][1];
                unsigned b0 = pk[2 * kk + 1][0], b1 = pk[2 * kk + 1][1];
                asm("v_permlane32_swap_b32 %0, %1" : "+v"(a0), "+v"(b0));
                asm("v_permlane16_swap_b32 %0, %1" : "+v"(a0), "+v"(b0));
                asm("v_permlane32_swap_b32 %0, %1" : "+v"(a1), "+v"(b1));
                asm("v_permlane16_swap_b32 %0, %1" : "+v"(a1), "+v"(b1));
                u32x4 words = {a0, a1, b0, b1};   // j01, j23, j45, j67
                pb[f][kk] = __builtin_bit_cast(bf16x8, words);
            }
        }

        // ---- PV swapped: O^T += V^T P^T. Each V-frag read feeds both frags.
        __builtin_amdgcn_s_setprio(1);
        #pragma unroll
        for (int t = 0; t < 4; ++t) {
            #pragma unroll
            for (int kk = 0; kk < 2; ++kk) {
                bf16x8 vb = *(const bf16x8*)(vbase + swz(t * 16 + l16, kk * 64 + lhi * 16));
                o_acc[0][t] = __builtin_amdgcn_mfma_f32_16x16x32_bf16(vb, pb[0][kk], o_acc[0][t], 0, 0, 0);
                o_acc[1][t] = __builtin_amdgcn_mfma_f32_16x16x32_bf16(vb, pb[1][kk], o_acc[1][t], 0, 0, 0);
            }
        }
        __builtin_amdgcn_s_setprio(0);

        // regs -> LDS for next tile; vmcnt paid HERE (after full compute phase)
        if (more) write_tile(cur ^ 1);
        cur ^= 1;
    }

    // ---- epilogue: finish l across lhi groups, store per fragment ----
    #pragma unroll
    for (int f = 0; f < 2; ++f) {
        float l = l_part[f];
        l += __shfl_xor(l, 16, 64);
        l += __shfl_xor(l, 32, 64);
        const int qrow = qrow0 + f * 16;
        if constexpr (SPLITK) {
            if (lhi == 0) {
                const size_t slot = ((((size_t)split * B_ + b) * Q_ + qrow) * H_ + h) * 2;
                ml[slot] = m_r[f]; ml[slot + 1] = l;
            }
            bf16_t* pop = po + ((((size_t)split * B_ + b) * Q_ + qrow) * H_ + h) * D_;
            #pragma unroll
            for (int t = 0; t < 4; ++t) {
                bf16x4 w;
                #pragma unroll
                for (int r = 0; r < 4; ++r) w[r] = (bf16_t)o_acc[f][t][r];
                *(bf16x4*)(pop + t * 16 + lhi * 4) = w;
            }
        } else {
            const float inv = 1.f / l;
            float* op = out + (((size_t)b * Q_ + qrow) * H_ + h) * D_;
            #pragma unroll
            for (int t = 0; t < 4; ++t) {
                f32x4 res = o_acc[f][t];
                #pragma unroll
                for (int r = 0; r < 4; ++r) res[r] *= inv;
                *(f32x4*)(op + t * 16 + lhi * 4) = res;
            }
        }
    }
}

// Merge the two splits: out = (2^(m0-M) O0 + 2^(m1-M) O1) / (2^(m0-M) l0 + 2^(m1-M) l1).
__global__ __launch_bounds__(256) void attn_combine(
    const bf16_t* __restrict__ po, const float* __restrict__ ml,
    float* __restrict__ out)
{
    const int idx  = blockIdx.x * 256 + threadIdx.x;   // < BQH*16
    const int dv   = idx & 15;                         // which f32x4 within D
    const int slot = idx >> 4;                         // (b*Q+q)*H+h
    const float2 ml0 = ((const float2*)ml)[slot];
    const float2 ml1 = ((const float2*)ml)[BQH + slot];
    const float M   = fmaxf(ml0.x, ml1.x);
    const float c0  = exp2f(ml0.x - M);
    const float c1  = exp2f(ml1.x - M);   // 0 exactly when split empty (m=-1e30)
    const float inv = 1.f / (c0 * ml0.y + c1 * ml1.y);
    bf16x4 p0 = *(const bf16x4*)(po + (size_t)slot * D_ + dv * 4);
    bf16x4 p1 = *(const bf16x4*)(po + (size_t)BQH * D_ + (size_t)slot * D_ + dv * 4);
    f32x4 o;
    #pragma unroll
    for (int r = 0; r < 4; ++r)
        o[r] = (c0 * (float)p0[r] + c1 * (float)p1[r]) * inv;
    *(f32x4*)(out + (size_t)slot * D_ + dv * 4) = o;
}

extern "C" void kernel_launch(void* const* d_in, const int* in_sizes, int n_in,
                              void* d_out, int out_size, void* d_ws, size_t ws_size,
                              hipStream_t stream) {
    const float* qs = (const float*)d_in[0];
    const float* ks = (const float*)d_in[1];
    const float* vs = (const float*)d_in[2];
    const int*   vl = (const int*)d_in[3];
    float*       out = (float*)d_out;

    const size_t po_bytes = (size_t)2 * BQH * D_ * sizeof(bf16_t);   // 16.78 MB
    const size_t ml_bytes = (size_t)2 * BQH * 2 * sizeof(float);     //  2.10 MB
    if (ws_size >= po_bytes + ml_bytes) {
        bf16_t* po = (bf16_t*)d_ws;
        float*  ml = (float*)((char*)d_ws + po_bytes);
        attn_fwd_kernel<true><<<dim3(16, 16, 2), 512, 0, stream>>>(qs, ks, vs, vl, nullptr, po, ml);
        attn_combine<<<dim3((BQH * 16) / 256), 256, 0, stream>>>(po, ml, out);
    } else {
        attn_fwd_kernel<false><<<dim3(8, 16, 2), 512, 0, stream>>>(qs, ks, vs, vl, out, nullptr, nullptr);
    }
}

// Round 13
// 67.173 us; speedup vs baseline: 1.7347x; 1.0938x over previous
//
#include <hip/hip_runtime.h>

#define B_ 2
#define Q_ 2048
#define K_ 2048
#define H_ 16
#define D_ 64
#define HD_ (H_ * D_)
#define BQH (B_ * Q_ * H_)

// Q pre-scale: (1/sqrt(64)) * log2(e)  -> scores in log2 units; softmax uses
// raw v_exp_f32 (2^x) with no per-element multiply.
#define QSCALE 0.18033688011112042f
#define DEFER_THR 10.0f   // log2-units; P bounded by 2^10, fine in bf16/f32

typedef __bf16 bf16_t;
typedef __attribute__((ext_vector_type(8))) __bf16 bf16x8;
typedef __attribute__((ext_vector_type(4))) __bf16 bf16x4;
typedef __attribute__((ext_vector_type(4))) float f32x4;

// Raw barrier: drains LDS ops only; global register-prefetch stays in flight.
#define SBAR() do {                                         \
    __builtin_amdgcn_sched_barrier(0);                      \
    asm volatile("s_waitcnt lgkmcnt(0)" ::: "memory");      \
    __builtin_amdgcn_s_barrier();                           \
    __builtin_amdgcn_sched_barrier(0);                      \
} while (0)

// Swizzled byte offset for a [N][64] bf16 tile (row stride 128 B).
// XOR bits 4-6 with row&7: bijective, keeps 16B granules, kills bank conflicts.
__device__ __forceinline__ int swz(int row, int colByte) {
    return (row * 128 + colByte) ^ ((row & 7) << 4);
}

// 512 threads = 8 waves; each wave owns 32 q rows (two 16-row fragments) so
// every K/V ds_read_b128 feeds TWO MFMAs and staging amortizes over 256 q
// rows. P goes through per-wave LDS (NO inline-asm permlane path: r10-r12
// showed it pins values to arch-VGPRs -> spill, VGPR=64 + WRITE_SIZE blowup;
// r3 measured this F=2 P-LDS structure at 120 VGPR, no spill).
template<bool SPLITK>
__global__ __launch_bounds__(512, 4) void attn_fwd_kernel(
    const float* __restrict__ qs, const float* __restrict__ ks,
    const float* __restrict__ vs, const int* __restrict__ valid_lens,
    float* __restrict__ out, bf16_t* __restrict__ po, float* __restrict__ ml)
{
    int qt, split;
    if constexpr (SPLITK) { qt = blockIdx.x >> 1; split = blockIdx.x & 1; }
    else                  { qt = blockIdx.x;      split = 0; }
    const int h    = blockIdx.y;
    const int b    = blockIdx.z;
    const int tid  = threadIdx.x;
    const int wave = tid >> 6;     // 0..7, each owns 32 q rows
    const int lane = tid & 63;
    const int l16  = lane & 15;
    const int lhi  = lane >> 4;    // 0..3

    const int valid  = valid_lens[b];
    const int ntiles = (valid + 63) >> 6;
    int tbeg = 0, tend = ntiles;
    if constexpr (SPLITK) {
        const int half = (ntiles + 1) >> 1;
        tbeg = split ? half : 0;
        tend = split ? ntiles : half;
    }

    const int qrow0 = qt * 256 + wave * 32 + l16;   // frag f adds +16

    if constexpr (SPLITK) {
        if (tbeg >= tend) {    // empty split: weight-0 sentinel
            if (lhi == 0) {
                #pragma unroll
                for (int f = 0; f < 2; ++f) {
                    const size_t slot = ((((size_t)split * B_ + b) * Q_ + qrow0 + f * 16) * H_ + h) * 2;
                    ml[slot] = -1e30f; ml[slot + 1] = 0.f;
                }
            }
            return;
        }
    }

    __shared__ bf16_t k_lds[2][64 * 64];    // [buf][key][d], swizzled
    __shared__ bf16_t v_lds[2][64 * 64];    // [buf][d][key] transposed, swizzled
    __shared__ bf16_t p_buf[8][32 * 64];    // per-wave P tile [qfrag*16+q][key], swizzled
    char* const pbase = (char*)&p_buf[wave][0];

    // ---- Q fragments (lane = row l16, k-dim d = dh*32+lhi*8+j), scale folded.
    bf16x8 a_q[2][2];
    #pragma unroll
    for (int f = 0; f < 2; ++f) {
        const float* qp = qs + (((size_t)b * Q_ + qrow0 + f * 16) * H_ + h) * D_;
        #pragma unroll
        for (int dh = 0; dh < 2; ++dh) {
            const f32x4* q4 = (const f32x4*)(qp + dh * 32 + lhi * 8);
            f32x4 lo = q4[0], hi = q4[1];
            #pragma unroll
            for (int j = 0; j < 4; ++j) {
                a_q[f][dh][j]     = (bf16_t)(lo[j] * QSCALE);
                a_q[f][dh][4 + j] = (bf16_t)(hi[j] * QSCALE);
            }
        }
    }

    // O accumulator (swapped PV C-layout): lane = q-col l16, d = t*16+lhi*4+r.
    f32x4 o_acc[2][4];
    #pragma unroll
    for (int f = 0; f < 2; ++f)
        #pragma unroll
        for (int t = 0; t < 4; ++t) o_acc[f][t] = (f32x4){0.f, 0.f, 0.f, 0.f};
    float m_r[2] = {-1e30f, -1e30f}, l_part[2] = {0.f, 0.f};

    const float* kb = ks + ((size_t)b * K_ * H_ + h) * D_;
    const float* vg = vs + ((size_t)b * K_ * H_ + h) * D_;

    // staging role split (wave-uniform): waves 0-3 stage K, waves 4-7 stage V
    const bool kRole = (tid < 256);
    const int  st    = kRole ? tid : (tid - 256);   // 0..255
    const int  krow  = st >> 2;                     // 0..63 (key)
    const int  kcolf = (st & 3) * 16;               // float col base
    const int  vr    = (st & 15) * 4;               // key base (4 rows)
    const int  vc    = (st >> 4) * 4;               // d base (4 cols)

    f32x4 reg[4];   // in-flight next tile (lives across the barrier)

    auto issue_loads = [&](int kt) {
        if (kRole) {
            const float* ksrc = kb + (size_t)(kt * 64 + krow) * HD_ + kcolf;
            #pragma unroll
            for (int i = 0; i < 4; ++i) reg[i] = ((const f32x4*)ksrc)[i];
        } else {
            #pragma unroll
            for (int i = 0; i < 4; ++i)
                reg[i] = *(const f32x4*)(vg + (size_t)(kt * 64 + vr + i) * HD_ + vc);
        }
    };

    auto write_tile = [&](int bi) {
        if (kRole) {
            char* kdst = (char*)&k_lds[bi][0];
            bf16x8 lo, hi;
            #pragma unroll
            for (int j = 0; j < 4; ++j) {
                lo[j] = (bf16_t)reg[0][j]; lo[4 + j] = (bf16_t)reg[1][j];
                hi[j] = (bf16_t)reg[2][j]; hi[4 + j] = (bf16_t)reg[3][j];
            }
            *(bf16x8*)(kdst + swz(krow, kcolf * 2))      = lo;
            *(bf16x8*)(kdst + swz(krow, kcolf * 2 + 16)) = hi;
        } else {
            char* vdst = (char*)&v_lds[bi][0];
            #pragma unroll
            for (int j = 0; j < 4; ++j) {
                bf16x4 w;
                w[0] = (bf16_t)reg[0][j]; w[1] = (bf16_t)reg[1][j];
                w[2] = (bf16_t)reg[2][j]; w[3] = (bf16_t)reg[3][j];
                *(bf16x4*)(vdst + swz(vc + j, vr * 2)) = w;
            }
        }
    };

    // prologue: first tile straight to LDS
    issue_loads(tbeg);
    write_tile(0);
    int cur = 0;

    for (int kt = tbeg; kt < tend; ++kt) {
        const bool more = (kt + 1 < tend);
        if (more) issue_loads(kt + 1);   // in flight across SBAR (no vmcnt drain)
        SBAR();

        char* const kbase = (char*)&k_lds[cur][0];
        char* const vbase = (char*)&v_lds[cur][0];

        // ---- S^T = K Q^T: lane = q-row l16, keys n*16+lhi*4+r. Each K-frag
        // read feeds BOTH q-fragments.
        f32x4 s[2][4];
        #pragma unroll
        for (int f = 0; f < 2; ++f)
            #pragma unroll
            for (int n = 0; n < 4; ++n) s[f][n] = (f32x4){0.f, 0.f, 0.f, 0.f};
        __builtin_amdgcn_s_setprio(1);
        #pragma unroll
        for (int n = 0; n < 4; ++n) {
            #pragma unroll
            for (int dh = 0; dh < 2; ++dh) {
                bf16x8 ak = *(const bf16x8*)(kbase + swz(n * 16 + l16, dh * 64 + lhi * 16));
                s[0][n] = __builtin_amdgcn_mfma_f32_16x16x32_bf16(ak, a_q[0][dh], s[0][n], 0, 0, 0);
                s[1][n] = __builtin_amdgcn_mfma_f32_16x16x32_bf16(ak, a_q[1][dh], s[1][n], 0, 0, 0);
            }
        }
        __builtin_amdgcn_s_setprio(0);

        // ---- mask only on the boundary tile (uniform branch) ----
        if (kt * 64 + 64 > valid) {
            #pragma unroll
            for (int n = 0; n < 4; ++n) {
                const int kbase_i = kt * 64 + n * 16 + lhi * 4;
                #pragma unroll
                for (int r = 0; r < 4; ++r)
                    if (kbase_i + r >= valid) { s[0][n][r] = -1e30f; s[1][n][r] = -1e30f; }
            }
        }

        // ---- deferred-max online softmax, per-fragment lane-local state ----
        float lm[2];
        #pragma unroll
        for (int f = 0; f < 2; ++f) {
            lm[f] = s[f][0][0];
            #pragma unroll
            for (int n = 0; n < 4; ++n)
                #pragma unroll
                for (int r = 0; r < 4; ++r) lm[f] = fmaxf(lm[f], s[f][n][r]);
        }
        if (__any((lm[0] > m_r[0] + DEFER_THR) || (lm[1] > m_r[1] + DEFER_THR))) {
            #pragma unroll
            for (int f = 0; f < 2; ++f) {
                float rm = fmaxf(lm[f], __shfl_xor(lm[f], 16, 64));
                rm = fmaxf(rm, __shfl_xor(rm, 32, 64));
                const float mnew  = fmaxf(m_r[f], rm);
                const float alpha = __builtin_amdgcn_exp2f(m_r[f] - mnew);
                m_r[f] = mnew;
                l_part[f] *= alpha;
                #pragma unroll
                for (int t = 0; t < 4; ++t) o_acc[f][t] *= alpha;
            }
        }

        // ---- P = 2^(s-m) -> wave-private LDS (b64 writes), read back as
        // B-fragments (b128). No cross-wave barrier needed.
        #pragma unroll
        for (int f = 0; f < 2; ++f) {
            float psum = 0.f;
            #pragma unroll
            for (int n = 0; n < 4; ++n) {
                bf16x4 w;
                #pragma unroll
                for (int r = 0; r < 4; ++r) {
                    const float e = __builtin_amdgcn_exp2f(s[f][n][r] - m_r[f]);
                    psum += e;
                    w[r] = (bf16_t)e;
                }
                *(bf16x4*)(pbase + swz(f * 16 + l16, n * 32 + lhi * 8)) = w;
            }
            l_part[f] += psum;
        }
        bf16x8 pb[2][2];
        #pragma unroll
        for (int f = 0; f < 2; ++f)
            #pragma unroll
            for (int kk = 0; kk < 2; ++kk)
                pb[f][kk] = *(const bf16x8*)(pbase + swz(f * 16 + l16, kk * 64 + lhi * 16));

        // ---- PV swapped: O^T += V^T P^T. Each V-frag read feeds BOTH frags.
        __builtin_amdgcn_s_setprio(1);
        #pragma unroll
        for (int t = 0; t < 4; ++t) {
            #pragma unroll
            for (int kk = 0; kk < 2; ++kk) {
                bf16x8 vb = *(const bf16x8*)(vbase + swz(t * 16 + l16, kk * 64 + lhi * 16));
                o_acc[0][t] = __builtin_amdgcn_mfma_f32_16x16x32_bf16(vb, pb[0][kk], o_acc[0][t], 0, 0, 0);
                o_acc[1][t] = __builtin_amdgcn_mfma_f32_16x16x32_bf16(vb, pb[1][kk], o_acc[1][t], 0, 0, 0);
            }
        }
        __builtin_amdgcn_s_setprio(0);

        // regs -> LDS for next tile; vmcnt paid HERE (after full compute phase)
        if (more) write_tile(cur ^ 1);
        cur ^= 1;
    }

    // ---- epilogue: finish l across lhi groups, store per fragment ----
    #pragma unroll
    for (int f = 0; f < 2; ++f) {
        float l = l_part[f];
        l += __shfl_xor(l, 16, 64);
        l += __shfl_xor(l, 32, 64);
        const int qrow = qrow0 + f * 16;
        if constexpr (SPLITK) {
            if (lhi == 0) {
                const size_t slot = ((((size_t)split * B_ + b) * Q_ + qrow) * H_ + h) * 2;
                ml[slot] = m_r[f]; ml[slot + 1] = l;
            }
            bf16_t* pop = po + ((((size_t)split * B_ + b) * Q_ + qrow) * H_ + h) * D_;
            #pragma unroll
            for (int t = 0; t < 4; ++t) {
                bf16x4 w;
                #pragma unroll
                for (int r = 0; r < 4; ++r) w[r] = (bf16_t)o_acc[f][t][r];
                *(bf16x4*)(pop + t * 16 + lhi * 4) = w;
            }
        } else {
            const float inv = 1.f / l;
            float* op = out + (((size_t)b * Q_ + qrow) * H_ + h) * D_;
            #pragma unroll
            for (int t = 0; t < 4; ++t) {
                f32x4 res = o_acc[f][t];
                #pragma unroll
                for (int r = 0; r < 4; ++r) res[r] *= inv;
                *(f32x4*)(op + t * 16 + lhi * 4) = res;
            }
        }
    }
}

// Merge the two splits: out = (2^(m0-M) O0 + 2^(m1-M) O1) / (2^(m0-M) l0 + 2^(m1-M) l1).
__global__ __launch_bounds__(256) void attn_combine(
    const bf16_t* __restrict__ po, const float* __restrict__ ml,
    float* __restrict__ out)
{
    const int idx  = blockIdx.x * 256 + threadIdx.x;   // < BQH*16
    const int dv   = idx & 15;                         // which f32x4 within D
    const int slot = idx >> 4;                         // (b*Q+q)*H+h
    const float2 ml0 = ((const float2*)ml)[slot];
    const float2 ml1 = ((const float2*)ml)[BQH + slot];
    const float M   = fmaxf(ml0.x, ml1.x);
    const float c0  = exp2f(ml0.x - M);
    const float c1  = exp2f(ml1.x - M);   // 0 exactly when split empty (m=-1e30)
    const float inv = 1.f / (c0 * ml0.y + c1 * ml1.y);
    bf16x4 p0 = *(const bf16x4*)(po + (size_t)slot * D_ + dv * 4);
    bf16x4 p1 = *(const bf16x4*)(po + (size_t)BQH * D_ + (size_t)slot * D_ + dv * 4);
    f32x4 o;
    #pragma unroll
    for (int r = 0; r < 4; ++r)
        o[r] = (c0 * (float)p0[r] + c1 * (float)p1[r]) * inv;
    *(f32x4*)(out + (size_t)slot * D_ + dv * 4) = o;
}

extern "C" void kernel_launch(void* const* d_in, const int* in_sizes, int n_in,
                              void* d_out, int out_size, void* d_ws, size_t ws_size,
                              hipStream_t stream) {
    const float* qs = (const float*)d_in[0];
    const float* ks = (const float*)d_in[1];
    const float* vs = (const float*)d_in[2];
    const int*   vl = (const int*)d_in[3];
    float*       out = (float*)d_out;

    const size_t po_bytes = (size_t)2 * BQH * D_ * sizeof(bf16_t);   // 16.78 MB
    const size_t ml_bytes = (size_t)2 * BQH * 2 * sizeof(float);     //  2.10 MB
    if (ws_size >= po_bytes + ml_bytes) {
        bf16_t* po = (bf16_t*)d_ws;
        float*  ml = (float*)((char*)d_ws + po_bytes);
        attn_fwd_kernel<true><<<dim3(16, 16, 2), 512, 0, stream>>>(qs, ks, vs, vl, nullptr, po, ml);
        attn_combine<<<dim3((BQH * 16) / 256), 256, 0, stream>>>(po, ml, out);
    } else {
        attn_fwd_kernel<false><<<dim3(8, 16, 2), 512, 0, stream>>>(qs, ks, vs, vl, out, nullptr, nullptr);
    }
}

// Round 14
// 49.911 us; speedup vs baseline: 2.3347x; 1.3459x over previous
//
#include <hip/hip_runtime.h>

#define B_ 2
#define Q_ 2048
#define K_ 2048
#define H_ 16
#define D_ 64
#define HD_ (H_ * D_)
#define BQH (B_ * Q_ * H_)

// Q pre-scale: (1/sqrt(64)) * log2(e)  -> scores in log2 units; softmax uses
// raw v_exp_f32 (2^x) with no per-element multiply.
#define QSCALE 0.18033688011112042f
#define DEFER_THR 10.0f   // log2-units; P bounded by 2^10, fine in bf16/f32

typedef __bf16 bf16_t;
typedef __attribute__((ext_vector_type(8))) __bf16 bf16x8;
typedef __attribute__((ext_vector_type(4))) __bf16 bf16x4;
typedef __attribute__((ext_vector_type(4))) float f32x4;

// Raw barrier: drains LDS ops only; global register-prefetch stays in flight.
#define SBAR() do {                                         \
    __builtin_amdgcn_sched_barrier(0);                      \
    asm volatile("s_waitcnt lgkmcnt(0)" ::: "memory");      \
    __builtin_amdgcn_s_barrier();                           \
    __builtin_amdgcn_sched_barrier(0);                      \
} while (0)

// Swizzled byte offset for a [N][64] bf16 tile (row stride 128 B).
// XOR bits 4-6 with row&7: bijective, keeps 16B granules, kills bank conflicts.
__device__ __forceinline__ int swz(int row, int colByte) {
    return (row * 128 + colByte) ^ ((row & 7) << 4);
}

// 256 threads = 4 waves; each wave owns 32 q rows (two 16-row fragments) so
// every K/V ds_read_b128 feeds TWO MFMAs. P via per-wave LDS.
// SINGLE-ARG launch bounds: two-arg (N,4) squeezed arch-VGPRs to 64 on this
// toolchain and spilled ~50 regs/thread (r9-r13: WRITE_SIZE blowups). r3/r4
// with __launch_bounds__(256) measured 120-124 VGPR, zero spill.
template<bool SPLITK>
__global__ __launch_bounds__(256) void attn_fwd_kernel(
    const float* __restrict__ qs, const float* __restrict__ ks,
    const float* __restrict__ vs, const int* __restrict__ valid_lens,
    float* __restrict__ out, bf16_t* __restrict__ po, float* __restrict__ ml)
{
    int qt, split;
    if constexpr (SPLITK) { qt = blockIdx.x >> 1; split = blockIdx.x & 1; }
    else                  { qt = blockIdx.x;      split = 0; }
    const int h    = blockIdx.y;
    const int b    = blockIdx.z;
    const int tid  = threadIdx.x;
    const int wave = tid >> 6;     // 0..3, each owns 32 q rows
    const int lane = tid & 63;
    const int l16  = lane & 15;
    const int lhi  = lane >> 4;    // 0..3

    const int valid  = valid_lens[b];
    const int ntiles = (valid + 63) >> 6;
    int tbeg = 0, tend = ntiles;
    if constexpr (SPLITK) {
        const int half = (ntiles + 1) >> 1;
        tbeg = split ? half : 0;
        tend = split ? ntiles : half;
    }

    const int qrow0 = qt * 128 + wave * 32 + l16;   // frag f adds +16

    if constexpr (SPLITK) {
        if (tbeg >= tend) {    // empty split: weight-0 sentinel
            if (lhi == 0) {
                #pragma unroll
                for (int f = 0; f < 2; ++f) {
                    const size_t slot = ((((size_t)split * B_ + b) * Q_ + qrow0 + f * 16) * H_ + h) * 2;
                    ml[slot] = -1e30f; ml[slot + 1] = 0.f;
                }
            }
            return;
        }
    }

    __shared__ bf16_t k_lds[2][64 * 64];    // [buf][key][d], swizzled
    __shared__ bf16_t v_lds[2][64 * 64];    // [buf][d][key] transposed, swizzled
    __shared__ bf16_t p_buf[4][32 * 64];    // per-wave P tile [qfrag*16+q][key], swizzled
    char* const pbase = (char*)&p_buf[wave][0];

    // ---- Q fragments (lane = row l16, k-dim d = dh*32+lhi*8+j), scale folded.
    bf16x8 a_q[2][2];
    #pragma unroll
    for (int f = 0; f < 2; ++f) {
        const float* qp = qs + (((size_t)b * Q_ + qrow0 + f * 16) * H_ + h) * D_;
        #pragma unroll
        for (int dh = 0; dh < 2; ++dh) {
            const f32x4* q4 = (const f32x4*)(qp + dh * 32 + lhi * 8);
            f32x4 lo = q4[0], hi = q4[1];
            #pragma unroll
            for (int j = 0; j < 4; ++j) {
                a_q[f][dh][j]     = (bf16_t)(lo[j] * QSCALE);
                a_q[f][dh][4 + j] = (bf16_t)(hi[j] * QSCALE);
            }
        }
    }

    // O accumulator (swapped PV C-layout): lane = q-col l16, d = t*16+lhi*4+r.
    f32x4 o_acc[2][4];
    #pragma unroll
    for (int f = 0; f < 2; ++f)
        #pragma unroll
        for (int t = 0; t < 4; ++t) o_acc[f][t] = (f32x4){0.f, 0.f, 0.f, 0.f};
    float m_r[2] = {-1e30f, -1e30f}, l_part[2] = {0.f, 0.f};

    const float* kb = ks + ((size_t)b * K_ * H_ + h) * D_;
    const float* vg = vs + ((size_t)b * K_ * H_ + h) * D_;

    // staging maps (r3-proven): every thread stages K (kreg[4]) and V (vreg[4])
    const int krow  = tid >> 2;          // 0..63 (key)
    const int kcolf = (tid & 3) * 16;    // float col base
    const int vr    = (tid & 15) * 4;    // key base (4 rows)
    const int vc    = (tid >> 4) * 4;    // d base (4 cols)

    f32x4 kreg[4], vreg[4];   // in-flight next tile (lives across the barrier)

    auto issue_loads = [&](int kt) {
        const float* ksrc = kb + (size_t)(kt * 64 + krow) * HD_ + kcolf;
        #pragma unroll
        for (int i = 0; i < 4; ++i) kreg[i] = ((const f32x4*)ksrc)[i];
        #pragma unroll
        for (int i = 0; i < 4; ++i)
            vreg[i] = *(const f32x4*)(vg + (size_t)(kt * 64 + vr + i) * HD_ + vc);
    };

    auto write_tile = [&](int bi) {
        char* kdst = (char*)&k_lds[bi][0];
        char* vdst = (char*)&v_lds[bi][0];
        bf16x8 lo, hi;
        #pragma unroll
        for (int j = 0; j < 4; ++j) {
            lo[j] = (bf16_t)kreg[0][j]; lo[4 + j] = (bf16_t)kreg[1][j];
            hi[j] = (bf16_t)kreg[2][j]; hi[4 + j] = (bf16_t)kreg[3][j];
        }
        *(bf16x8*)(kdst + swz(krow, kcolf * 2))      = lo;
        *(bf16x8*)(kdst + swz(krow, kcolf * 2 + 16)) = hi;
        #pragma unroll
        for (int j = 0; j < 4; ++j) {
            bf16x4 w;
            w[0] = (bf16_t)vreg[0][j]; w[1] = (bf16_t)vreg[1][j];
            w[2] = (bf16_t)vreg[2][j]; w[3] = (bf16_t)vreg[3][j];
            *(bf16x4*)(vdst + swz(vc + j, vr * 2)) = w;
        }
    };

    // prologue: first tile straight to LDS
    issue_loads(tbeg);
    write_tile(0);
    int cur = 0;

    for (int kt = tbeg; kt < tend; ++kt) {
        const bool more = (kt + 1 < tend);
        if (more) issue_loads(kt + 1);   // in flight across SBAR (no vmcnt drain)
        SBAR();

        char* const kbase = (char*)&k_lds[cur][0];
        char* const vbase = (char*)&v_lds[cur][0];

        // ---- S^T = K Q^T: lane = q-row l16, keys n*16+lhi*4+r. Each K-frag
        // read feeds BOTH q-fragments.
        f32x4 s[2][4];
        #pragma unroll
        for (int f = 0; f < 2; ++f)
            #pragma unroll
            for (int n = 0; n < 4; ++n) s[f][n] = (f32x4){0.f, 0.f, 0.f, 0.f};
        __builtin_amdgcn_s_setprio(1);
        #pragma unroll
        for (int n = 0; n < 4; ++n) {
            #pragma unroll
            for (int dh = 0; dh < 2; ++dh) {
                bf16x8 ak = *(const bf16x8*)(kbase + swz(n * 16 + l16, dh * 64 + lhi * 16));
                s[0][n] = __builtin_amdgcn_mfma_f32_16x16x32_bf16(ak, a_q[0][dh], s[0][n], 0, 0, 0);
                s[1][n] = __builtin_amdgcn_mfma_f32_16x16x32_bf16(ak, a_q[1][dh], s[1][n], 0, 0, 0);
            }
        }
        __builtin_amdgcn_s_setprio(0);

        // ---- mask only on the boundary tile (uniform branch) ----
        if (kt * 64 + 64 > valid) {
            #pragma unroll
            for (int n = 0; n < 4; ++n) {
                const int kbase_i = kt * 64 + n * 16 + lhi * 4;
                #pragma unroll
                for (int r = 0; r < 4; ++r)
                    if (kbase_i + r >= valid) { s[0][n][r] = -1e30f; s[1][n][r] = -1e30f; }
            }
        }

        // ---- deferred-max online softmax, per-fragment lane-local state ----
        float lm[2];
        #pragma unroll
        for (int f = 0; f < 2; ++f) {
            lm[f] = s[f][0][0];
            #pragma unroll
            for (int n = 0; n < 4; ++n)
                #pragma unroll
                for (int r = 0; r < 4; ++r) lm[f] = fmaxf(lm[f], s[f][n][r]);
        }
        if (__any((lm[0] > m_r[0] + DEFER_THR) || (lm[1] > m_r[1] + DEFER_THR))) {
            #pragma unroll
            for (int f = 0; f < 2; ++f) {
                float rm = fmaxf(lm[f], __shfl_xor(lm[f], 16, 64));
                rm = fmaxf(rm, __shfl_xor(rm, 32, 64));
                const float mnew  = fmaxf(m_r[f], rm);
                const float alpha = __builtin_amdgcn_exp2f(m_r[f] - mnew);
                m_r[f] = mnew;
                l_part[f] *= alpha;
                #pragma unroll
                for (int t = 0; t < 4; ++t) o_acc[f][t] *= alpha;
            }
        }

        // ---- P = 2^(s-m) -> wave-private LDS (b64 writes), read back as
        // B-fragments (b128). No cross-wave barrier needed.
        #pragma unroll
        for (int f = 0; f < 2; ++f) {
            float psum = 0.f;
            #pragma unroll
            for (int n = 0; n < 4; ++n) {
                bf16x4 w;
                #pragma unroll
                for (int r = 0; r < 4; ++r) {
                    const float e = __builtin_amdgcn_exp2f(s[f][n][r] - m_r[f]);
                    psum += e;
                    w[r] = (bf16_t)e;
                }
                *(bf16x4*)(pbase + swz(f * 16 + l16, n * 32 + lhi * 8)) = w;
            }
            l_part[f] += psum;
        }
        bf16x8 pb[2][2];
        #pragma unroll
        for (int f = 0; f < 2; ++f)
            #pragma unroll
            for (int kk = 0; kk < 2; ++kk)
                pb[f][kk] = *(const bf16x8*)(pbase + swz(f * 16 + l16, kk * 64 + lhi * 16));

        // ---- PV swapped: O^T += V^T P^T. Each V-frag read feeds BOTH frags.
        __builtin_amdgcn_s_setprio(1);
        #pragma unroll
        for (int t = 0; t < 4; ++t) {
            #pragma unroll
            for (int kk = 0; kk < 2; ++kk) {
                bf16x8 vb = *(const bf16x8*)(vbase + swz(t * 16 + l16, kk * 64 + lhi * 16));
                o_acc[0][t] = __builtin_amdgcn_mfma_f32_16x16x32_bf16(vb, pb[0][kk], o_acc[0][t], 0, 0, 0);
                o_acc[1][t] = __builtin_amdgcn_mfma_f32_16x16x32_bf16(vb, pb[1][kk], o_acc[1][t], 0, 0, 0);
            }
        }
        __builtin_amdgcn_s_setprio(0);

        // regs -> LDS for next tile; vmcnt paid HERE (after full compute phase)
        if (more) write_tile(cur ^ 1);
        cur ^= 1;
    }

    // ---- epilogue: finish l across lhi groups, store per fragment ----
    #pragma unroll
    for (int f = 0; f < 2; ++f) {
        float l = l_part[f];
        l += __shfl_xor(l, 16, 64);
        l += __shfl_xor(l, 32, 64);
        const int qrow = qrow0 + f * 16;
        if constexpr (SPLITK) {
            if (lhi == 0) {
                const size_t slot = ((((size_t)split * B_ + b) * Q_ + qrow) * H_ + h) * 2;
                ml[slot] = m_r[f]; ml[slot + 1] = l;
            }
            bf16_t* pop = po + ((((size_t)split * B_ + b) * Q_ + qrow) * H_ + h) * D_;
            #pragma unroll
            for (int t = 0; t < 4; ++t) {
                bf16x4 w;
                #pragma unroll
                for (int r = 0; r < 4; ++r) w[r] = (bf16_t)o_acc[f][t][r];
                *(bf16x4*)(pop + t * 16 + lhi * 4) = w;
            }
        } else {
            const float inv = 1.f / l;
            float* op = out + (((size_t)b * Q_ + qrow) * H_ + h) * D_;
            #pragma unroll
            for (int t = 0; t < 4; ++t) {
                f32x4 res = o_acc[f][t];
                #pragma unroll
                for (int r = 0; r < 4; ++r) res[r] *= inv;
                *(f32x4*)(op + t * 16 + lhi * 4) = res;
            }
        }
    }
}

// Merge the two splits: out = (2^(m0-M) O0 + 2^(m1-M) O1) / (2^(m0-M) l0 + 2^(m1-M) l1).
__global__ __launch_bounds__(256) void attn_combine(
    const bf16_t* __restrict__ po, const float* __restrict__ ml,
    float* __restrict__ out)
{
    const int idx  = blockIdx.x * 256 + threadIdx.x;   // < BQH*16
    const int dv   = idx & 15;                         // which f32x4 within D
    const int slot = idx >> 4;                         // (b*Q+q)*H+h
    const float2 ml0 = ((const float2*)ml)[slot];
    const float2 ml1 = ((const float2*)ml)[BQH + slot];
    const float M   = fmaxf(ml0.x, ml1.x);
    const float c0  = exp2f(ml0.x - M);
    const float c1  = exp2f(ml1.x - M);   // 0 exactly when split empty (m=-1e30)
    const float inv = 1.f / (c0 * ml0.y + c1 * ml1.y);
    bf16x4 p0 = *(const bf16x4*)(po + (size_t)slot * D_ + dv * 4);
    bf16x4 p1 = *(const bf16x4*)(po + (size_t)BQH * D_ + (size_t)slot * D_ + dv * 4);
    f32x4 o;
    #pragma unroll
    for (int r = 0; r < 4; ++r)
        o[r] = (c0 * (float)p0[r] + c1 * (float)p1[r]) * inv;
    *(f32x4*)(out + (size_t)slot * D_ + dv * 4) = o;
}

extern "C" void kernel_launch(void* const* d_in, const int* in_sizes, int n_in,
                              void* d_out, int out_size, void* d_ws, size_t ws_size,
                              hipStream_t stream) {
    const float* qs = (const float*)d_in[0];
    const float* ks = (const float*)d_in[1];
    const float* vs = (const float*)d_in[2];
    const int*   vl = (const int*)d_in[3];
    float*       out = (float*)d_out;

    const size_t po_bytes = (size_t)2 * BQH * D_ * sizeof(bf16_t);   // 16.78 MB
    const size_t ml_bytes = (size_t)2 * BQH * 2 * sizeof(float);     //  2.10 MB
    if (ws_size >= po_bytes + ml_bytes) {
        bf16_t* po = (bf16_t*)d_ws;
        float*  ml = (float*)((char*)d_ws + po_bytes);
        attn_fwd_kernel<true><<<dim3(32, 16, 2), 256, 0, stream>>>(qs, ks, vs, vl, nullptr, po, ml);
        attn_combine<<<dim3((BQH * 16) / 256), 256, 0, stream>>>(po, ml, out);
    } else {
        attn_fwd_kernel<false><<<dim3(16, 16, 2), 256, 0, stream>>>(qs, ks, vs, vl, out, nullptr, nullptr);
    }
}

// Round 15
// 36.989 us; speedup vs baseline: 3.1503x; 1.3493x over previous
//
#include <hip/hip_runtime.h>

#define B_ 2
#define Q_ 2048
#define K_ 2048
#define H_ 16
#define D_ 64
#define HD_ (H_ * D_)

// Q pre-scale: (1/sqrt(64)) * log2(e)  -> scores in log2 units; softmax uses
// raw v_exp_f32 (2^x) with no per-element multiply.
#define QSCALE 0.18033688011112042f
#define DEFER_THR 10.0f   // log2-units; P bounded by 2^10, fine in bf16/f32

typedef __bf16 bf16_t;
typedef __attribute__((ext_vector_type(8))) __bf16 bf16x8;
typedef __attribute__((ext_vector_type(4))) __bf16 bf16x4;
typedef __attribute__((ext_vector_type(4))) float f32x4;
typedef __attribute__((ext_vector_type(4))) unsigned int u32x4;

// Raw barrier: drains LDS ops only; global register-prefetch stays in flight.
#define SBAR() do {                                         \
    __builtin_amdgcn_sched_barrier(0);                      \
    asm volatile("s_waitcnt lgkmcnt(0)" ::: "memory");      \
    __builtin_amdgcn_s_barrier();                           \
    __builtin_amdgcn_sched_barrier(0);                      \
} while (0)

// Swizzled byte offset for a [N][64] bf16 tile (row stride 128 B).
// XOR bits 4-6 with row&7: bijective, keeps 16B granules, kills bank conflicts.
__device__ __forceinline__ int swz(int row, int colByte) {
    return (row * 128 + colByte) ^ ((row & 7) << 4);
}

// r7 frame (512 threads / 8 waves / F=1 / BQ=128, monolith) with:
//  - SINGLE-ARG launch bounds (two-arg (N,4) capped arch-VGPRs at 64 on this
//    toolchain -> ~50 regs/thread scratch spill; r14 isolated & confirmed).
//  - P never touches LDS: cvt_pk_bf16 + permlane{32,16}_swap redistribute the
//    swapped-QK^T C-layout P into exact PV B-fragment layout in registers
//    (pure VALU; numerics verified r11: absmax unchanged, conflicts -> 0).
__global__ __launch_bounds__(512) void attn_fwd_kernel(
    const float* __restrict__ qs, const float* __restrict__ ks,
    const float* __restrict__ vs, const int* __restrict__ valid_lens,
    float* __restrict__ out)
{
    const int qt   = blockIdx.x;   // 128-row q tile
    const int h    = blockIdx.y;
    const int b    = blockIdx.z;
    const int tid  = threadIdx.x;
    const int lane = tid & 63;
    const int l16  = lane & 15;
    const int lhi  = lane >> 4;    // 0..3

    const int valid  = valid_lens[b];
    const int ntiles = (valid + 63) >> 6;   // tiles fully past valid contribute exactly 0

    __shared__ bf16_t k_lds[2][64 * 64];    // [buf][key][d], swizzled
    __shared__ bf16_t v_lds[2][64 * 64];    // [buf][d][key] transposed, swizzled

    // ---- Q fragment (lane = row l16, k-dim d = dh*32+lhi*8+j), scale folded.
    const int    qrow = qt * 128 + (tid >> 6) * 16 + l16;
    const float* qp   = qs + (((size_t)b * Q_ + qrow) * H_ + h) * D_;
    bf16x8 a_q[2];
    #pragma unroll
    for (int dh = 0; dh < 2; ++dh) {
        const f32x4* q4 = (const f32x4*)(qp + dh * 32 + lhi * 8);
        f32x4 lo = q4[0], hi = q4[1];
        #pragma unroll
        for (int j = 0; j < 4; ++j) {
            a_q[dh][j]     = (bf16_t)(lo[j] * QSCALE);
            a_q[dh][4 + j] = (bf16_t)(hi[j] * QSCALE);
        }
    }

    // O accumulator (swapped PV C-layout): lane = q-col l16, d = t*16+lhi*4+r.
    f32x4 o_acc[4];
    #pragma unroll
    for (int t = 0; t < 4; ++t) o_acc[t] = (f32x4){0.f, 0.f, 0.f, 0.f};
    float m_r = -1e30f, l_part = 0.f;

    const float* kb = ks + ((size_t)b * K_ * H_ + h) * D_;
    const float* vg = vs + ((size_t)b * K_ * H_ + h) * D_;

    // staging role split (wave-uniform): waves 0-3 stage K, waves 4-7 stage V
    const bool kRole = (tid < 256);
    const int  st    = kRole ? tid : (tid - 256);   // 0..255
    const int  krow  = st >> 2;                     // 0..63 (key)
    const int  kcolf = (st & 3) * 16;               // float col base
    const int  vr    = (st & 15) * 4;               // key base (4 rows)
    const int  vc    = (st >> 4) * 4;               // d base (4 cols)

    f32x4 reg[4];   // in-flight next tile (lives across the barrier)

    auto issue_loads = [&](int kt) {
        if (kRole) {
            const float* ksrc = kb + (size_t)(kt * 64 + krow) * HD_ + kcolf;
            #pragma unroll
            for (int i = 0; i < 4; ++i) reg[i] = ((const f32x4*)ksrc)[i];
        } else {
            #pragma unroll
            for (int i = 0; i < 4; ++i)
                reg[i] = *(const f32x4*)(vg + (size_t)(kt * 64 + vr + i) * HD_ + vc);
        }
    };

    auto write_tile = [&](int bi) {
        if (kRole) {
            char* kdst = (char*)&k_lds[bi][0];
            bf16x8 lo, hi;
            #pragma unroll
            for (int j = 0; j < 4; ++j) {
                lo[j] = (bf16_t)reg[0][j]; lo[4 + j] = (bf16_t)reg[1][j];
                hi[j] = (bf16_t)reg[2][j]; hi[4 + j] = (bf16_t)reg[3][j];
            }
            *(bf16x8*)(kdst + swz(krow, kcolf * 2))      = lo;
            *(bf16x8*)(kdst + swz(krow, kcolf * 2 + 16)) = hi;
        } else {
            char* vdst = (char*)&v_lds[bi][0];
            #pragma unroll
            for (int j = 0; j < 4; ++j) {
                bf16x4 w;
                w[0] = (bf16_t)reg[0][j]; w[1] = (bf16_t)reg[1][j];
                w[2] = (bf16_t)reg[2][j]; w[3] = (bf16_t)reg[3][j];
                *(bf16x4*)(vdst + swz(vc + j, vr * 2)) = w;
            }
        }
    };

    // prologue: tile 0 straight to LDS
    issue_loads(0);
    write_tile(0);
    int cur = 0;

    for (int kt = 0; kt < ntiles; ++kt) {
        const bool more = (kt + 1 < ntiles);
        if (more) issue_loads(kt + 1);   // stays in flight across SBAR (no vmcnt drain)
        SBAR();

        char* const kbase = (char*)&k_lds[cur][0];
        char* const vbase = (char*)&v_lds[cur][0];

        // ---- S^T = K Q^T (swapped): lane = q-row l16, keys n*16+lhi*4+r.
        f32x4 s[4];
        #pragma unroll
        for (int n = 0; n < 4; ++n) s[n] = (f32x4){0.f, 0.f, 0.f, 0.f};
        __builtin_amdgcn_s_setprio(1);
        #pragma unroll
        for (int n = 0; n < 4; ++n) {
            #pragma unroll
            for (int dh = 0; dh < 2; ++dh) {
                bf16x8 ak = *(const bf16x8*)(kbase + swz(n * 16 + l16, dh * 64 + lhi * 16));
                s[n] = __builtin_amdgcn_mfma_f32_16x16x32_bf16(ak, a_q[dh], s[n], 0, 0, 0);
            }
        }
        __builtin_amdgcn_s_setprio(0);

        // ---- mask only on the boundary tile (uniform branch) ----
        if (kt * 64 + 64 > valid) {
            #pragma unroll
            for (int n = 0; n < 4; ++n) {
                const int kbase_i = kt * 64 + n * 16 + lhi * 4;
                #pragma unroll
                for (int r = 0; r < 4; ++r)
                    if (kbase_i + r >= valid) s[n][r] = -1e30f;
            }
        }

        // ---- deferred-max online softmax, all state lane-local ----
        float lm = s[0][0];
        #pragma unroll
        for (int n = 0; n < 4; ++n)
            #pragma unroll
            for (int r = 0; r < 4; ++r) lm = fmaxf(lm, s[n][r]);
        if (__any(lm > m_r + DEFER_THR)) {   // rare, wave-uniform update
            float rm = fmaxf(lm, __shfl_xor(lm, 16, 64));
            rm = fmaxf(rm, __shfl_xor(rm, 32, 64));
            const float mnew  = fmaxf(m_r, rm);
            const float alpha = __builtin_amdgcn_exp2f(m_r - mnew);
            m_r = mnew;
            l_part *= alpha;
            #pragma unroll
            for (int t = 0; t < 4; ++t) o_acc[t] *= alpha;
        }

        // ---- P = 2^(s-m) -> bf16 B-fragments IN REGISTERS (no LDS):
        // cvt_pk packs pairs; permlane32+16 swaps move quads across lhi
        // groups so pb[kk] = keys kk*32 + lhi*8 + j (verified r11).
        bf16x8 pb[2];
        {
            float psum = 0.f;
            unsigned pk[4][2];
            #pragma unroll
            for (int n = 0; n < 4; ++n) {
                float e0 = __builtin_amdgcn_exp2f(s[n][0] - m_r);
                float e1 = __builtin_amdgcn_exp2f(s[n][1] - m_r);
                float e2 = __builtin_amdgcn_exp2f(s[n][2] - m_r);
                float e3 = __builtin_amdgcn_exp2f(s[n][3] - m_r);
                psum += (e0 + e1) + (e2 + e3);
                asm("v_cvt_pk_bf16_f32 %0, %1, %2" : "=v"(pk[n][0]) : "v"(e0), "v"(e1));
                asm("v_cvt_pk_bf16_f32 %0, %1, %2" : "=v"(pk[n][1]) : "v"(e2), "v"(e3));
            }
            l_part += psum;
            #pragma unroll
            for (int kk = 0; kk < 2; ++kk) {
                unsigned a0 = pk[2 * kk][0],     a1 = pk[2 * kk][1];
                unsigned b0 = pk[2 * kk + 1][0], b1 = pk[2 * kk + 1][1];
                asm("v_permlane32_swap_b32 %0, %1" : "+v"(a0), "+v"(b0));
                asm("v_permlane16_swap_b32 %0, %1" : "+v"(a0), "+v"(b0));
                asm("v_permlane32_swap_b32 %0, %1" : "+v"(a1), "+v"(b1));
                asm("v_permlane16_swap_b32 %0, %1" : "+v"(a1), "+v"(b1));
                u32x4 words = {a0, a1, b0, b1};   // j01, j23, j45, j67
                pb[kk] = __builtin_bit_cast(bf16x8, words);
            }
        }

        // ---- PV swapped: O^T += V^T P^T -> lane = q-col, d-rows ----
        __builtin_amdgcn_s_setprio(1);
        #pragma unroll
        for (int t = 0; t < 4; ++t) {
            #pragma unroll
            for (int kk = 0; kk < 2; ++kk) {
                bf16x8 vb = *(const bf16x8*)(vbase + swz(t * 16 + l16, kk * 64 + lhi * 16));
                o_acc[t] = __builtin_amdgcn_mfma_f32_16x16x32_bf16(vb, pb[kk], o_acc[t], 0, 0, 0);
            }
        }
        __builtin_amdgcn_s_setprio(0);

        // regs -> LDS for next tile; vmcnt paid HERE (after full compute phase)
        if (more) write_tile(cur ^ 1);
        cur ^= 1;
    }

    // ---- epilogue: finish l over the lhi group, divide, vector store ----
    float l = l_part;
    l += __shfl_xor(l, 16, 64);
    l += __shfl_xor(l, 32, 64);
    const float inv = 1.f / l;
    float* op = out + (((size_t)b * Q_ + qrow) * H_ + h) * D_;
    #pragma unroll
    for (int t = 0; t < 4; ++t) {
        f32x4 res = o_acc[t];
        #pragma unroll
        for (int r = 0; r < 4; ++r) res[r] *= inv;
        *(f32x4*)(op + t * 16 + lhi * 4) = res;
    }
}

extern "C" void kernel_launch(void* const* d_in, const int* in_sizes, int n_in,
                              void* d_out, int out_size, void* d_ws, size_t ws_size,
                              hipStream_t stream) {
    const float* qs = (const float*)d_in[0];
    const float* ks = (const float*)d_in[1];
    const float* vs = (const float*)d_in[2];
    const int*   vl = (const int*)d_in[3];
    float*       out = (float*)d_out;
    attn_fwd_kernel<<<dim3(Q_ / 128, H_, B_), 512, 0, stream>>>(qs, ks, vs, vl, out);
}